// Round 1
// baseline (259.470 us; speedup 1.0000x reference)
//
#include <hip/hip_runtime.h>

#define NBOND 96
#define HBS 158
#define NSTEP 288

__global__ __launch_bounds__(320, 2)
void gcn_mp_kernel(const int* __restrict__ a2b,
                   const int* __restrict__ b2a,
                   const int* __restrict__ b2revb,
                   const float* __restrict__ f_bonds,
                   const float* __restrict__ bond_sum,
                   const float* __restrict__ W0,
                   const float* __restrict__ b0,
                   const float* __restrict__ W1, const float* __restrict__ b1,
                   const float* __restrict__ W2, const float* __restrict__ b2v,
                   const float* __restrict__ W3, const float* __restrict__ b3,
                   const float* __restrict__ W4, const float* __restrict__ b4,
                   float* __restrict__ out)
{
  const int m = blockIdx.x;
  const int t = threadIdx.x;

  __shared__ __align__(16) float fb[NBOND * 160];   // rows padded to 160, cols 158/159 = 0
  __shared__ __align__(16) float xv[320];           // [0:160)=fb[c] (pad 0), [160:320)=bs (pad 0)
  __shared__ float bss[160];
  __shared__ float part[8 * 161];                   // stride 161: reads conflict-free
  __shared__ float hbuf[128];
  __shared__ int sD[NSTEP];
  __shared__ int sR[NSTEP];

  // ---- stage fb into LDS (pad cols >=158 with 0)
  for (int idx = t; idx < NBOND * 160; idx += 320) {
    int r = idx / 160, o = idx - r * 160;
    fb[idx] = (o < HBS) ? f_bonds[(m * NBOND + r) * HBS + o] : 0.f;
  }
  if (t < 160) bss[t] = (t < HBS) ? bond_sum[m * HBS + t] : 0.f;

  // ---- precompute per-step indices (addresses are data-independent)
  for (int i = t; i < NSTEP; i += 320) {
    int c = i / 3, j = i - c * 3;
    int a = b2a[m * NBOND + c];
    sD[i] = a2b[(m * NBOND + a) * 3 + j] - 1;   // d-1 in [0,96)
    sR[i] = b2revb[m * NBOND + c];
  }

  // ---- W0 fragments into registers: thread (og, s) holds rows og*4..og*4+3, k-slice [s*40, s*40+40)
  const int og = t >> 3;   // 0..39
  const int s  = t & 7;    // 0..7
  float w[4][40];
#pragma unroll
  for (int r = 0; r < 4; ++r) {
    const int o = og * 4 + r;
#pragma unroll
    for (int kk = 0; kk < 40; ++kk) {
      const int k = s * 40 + kk;                       // padded-K index, K=320
      const int col = (k < 160) ? k : (k - 2);         // [160,318) -> 158 + (k-160)
      const bool valid = (o < HBS) && ((k < 160) ? (k < HBS) : (k < 160 + HBS));
      w[r][kk] = valid ? W0[o * (2 * HBS) + col] : 0.f;
    }
  }

  __syncthreads();

  // ---- 288 sequential steps
#pragma unroll 1
  for (int i = 0; i < NSTEP; ++i) {
    const int c = i / 3;
    const int dm1 = sD[i];
    const int rv  = sR[i];

    if (t < 160) {
      float b = bss[t] + fb[dm1 * 160 + t] - fb[rv * 160 + t];
      bss[t] = b;
      xv[160 + t] = b;                 // rows 158/159 of fb are 0 -> pads stay 0
    } else {
      const int tt = t - 160;
      xv[tt] = fb[c * 160 + tt];
    }
    __syncthreads();

    float a0 = 0.f, a1 = 0.f, a2 = 0.f, a3 = 0.f;
    const float4* xq = (const float4*)(xv + s * 40);
#pragma unroll
    for (int q = 0; q < 10; ++q) {
      const float4 xx = xq[q];
      a0 = fmaf(w[0][4*q+0], xx.x, a0);
      a1 = fmaf(w[1][4*q+0], xx.x, a1);
      a2 = fmaf(w[2][4*q+0], xx.x, a2);
      a3 = fmaf(w[3][4*q+0], xx.x, a3);
      a0 = fmaf(w[0][4*q+1], xx.y, a0);
      a1 = fmaf(w[1][4*q+1], xx.y, a1);
      a2 = fmaf(w[2][4*q+1], xx.y, a2);
      a3 = fmaf(w[3][4*q+1], xx.y, a3);
      a0 = fmaf(w[0][4*q+2], xx.z, a0);
      a1 = fmaf(w[1][4*q+2], xx.z, a1);
      a2 = fmaf(w[2][4*q+2], xx.z, a2);
      a3 = fmaf(w[3][4*q+2], xx.z, a3);
      a0 = fmaf(w[0][4*q+3], xx.w, a0);
      a1 = fmaf(w[1][4*q+3], xx.w, a1);
      a2 = fmaf(w[2][4*q+3], xx.w, a2);
      a3 = fmaf(w[3][4*q+3], xx.w, a3);
    }
    const int pb = s * 161 + og * 4;
    part[pb + 0] = a0; part[pb + 1] = a1; part[pb + 2] = a2; part[pb + 3] = a3;
    __syncthreads();

    if (t < HBS) {
      float sum = b0[t];
#pragma unroll
      for (int ss = 0; ss < 8; ++ss) sum += part[ss * 161 + t];
      fb[c * 160 + t] = sum;           // new bond feature row
    }
    __syncthreads();
  }

  // ---- mp = sum over rows of fb
  if (t < 160) {
    float acc = 0.f;
#pragma unroll 1
    for (int r = 0; r < NBOND; ++r) acc += fb[r * 160 + t];
    xv[t] = acc;
  }
  __syncthreads();

  // ---- tiny MLP: 158 -> 110 (no relu) -> 70 (relu) -> 35 (relu) -> 1
  if (t < 110) {
    float acc = b1[t];
    for (int o = 0; o < HBS; ++o) acc = fmaf(xv[o], W1[t * HBS + o], acc);
    hbuf[t] = acc;
  }
  __syncthreads();
  if (t < 70) {
    float acc = b2v[t];
    for (int k = 0; k < 110; ++k) acc = fmaf(hbuf[k], W2[t * 110 + k], acc);
    part[t] = fmaxf(acc, 0.f);
  }
  __syncthreads();
  if (t < 35) {
    float acc = b3[t];
    for (int k = 0; k < 70; ++k) acc = fmaf(part[k], W3[t * 70 + k], acc);
    xv[200 + t] = fmaxf(acc, 0.f);
  }
  __syncthreads();
  if (t == 0) {
    float acc = b4[0];
    for (int k = 0; k < 35; ++k) acc = fmaf(xv[200 + k], W4[k], acc);
    out[m] = acc;
  }
}

extern "C" void kernel_launch(void* const* d_in, const int* in_sizes, int n_in,
                              void* d_out, int out_size, void* d_ws, size_t ws_size,
                              hipStream_t stream)
{
  const int*   a2b      = (const int*)d_in[0];
  const int*   b2a      = (const int*)d_in[1];
  const int*   b2revb   = (const int*)d_in[2];
  const float* f_bonds  = (const float*)d_in[3];
  /* d_in[4] = f_atoms_ (unused by forward) */
  const float* bond_sum = (const float*)d_in[5];
  const float* W0 = (const float*)d_in[6];
  const float* b0 = (const float*)d_in[7];
  const float* W1 = (const float*)d_in[8];
  const float* b1 = (const float*)d_in[9];
  const float* W2 = (const float*)d_in[10];
  const float* b2 = (const float*)d_in[11];
  const float* W3 = (const float*)d_in[12];
  const float* b3 = (const float*)d_in[13];
  const float* W4 = (const float*)d_in[14];
  const float* b4 = (const float*)d_in[15];

  gcn_mp_kernel<<<dim3(96), dim3(320), 0, stream>>>(
      a2b, b2a, b2revb, f_bonds, bond_sum,
      W0, b0, W1, b1, W2, b2, W3, b3, W4, b4,
      (float*)d_out);
}